// Round 8
// baseline (681.503 us; speedup 1.0000x reference)
//
#include <hip/hip_runtime.h>
#include <cstdint>
#include <cstddef>

// Problem constants
#define NB 4
#define NC 256
#define NP 1024
#define NT 64
#define NH 8
#define ND 32
#define NF 2048            // ND*NT, joint contraction dim
#define NPT 65536          // NP*NT
#define KQV_ELEMS 67108864ull   // 32*1024*2048
#define INV_SCALE 0.022097086912079608f  // 1/sqrt(2048)

typedef unsigned short u16;
typedef __bf16 bf16x8 __attribute__((ext_vector_type(8)));
typedef short  s16x8  __attribute__((ext_vector_type(8)));
typedef short  s16x4  __attribute__((ext_vector_type(4)));
typedef float  f32x4  __attribute__((ext_vector_type(4)));

__device__ __forceinline__ u16 f2bf(float f) {
  unsigned u = __builtin_bit_cast(unsigned, f);
  u += 0x7fffu + ((u >> 16) & 1u);        // RNE
  return (u16)(u >> 16);
}
__device__ __forceinline__ float bf2f(u16 h) {
  unsigned u = ((unsigned)h) << 16;
  return __builtin_bit_cast(float, u);
}
// LDS XOR swizzle for transpose staging (byte XOR mask, bits 4..6)
__device__ __forceinline__ int swz(int row) { return ((row ^ (row >> 3)) & 7) << 4; }

#define GLOAD_LDS16(gp, lp) __builtin_amdgcn_global_load_lds( \
    (const __attribute__((address_space(1))) void*)(gp),      \
    (__attribute__((address_space(3))) void*)(lp), 16, 0, 0)

__device__ __forceinline__ f32x4 mfma16(bf16x8 a, bf16x8 b, f32x4 c) {
  return __builtin_amdgcn_mfma_f32_16x16x32_bf16(a, b, c, 0, 0, 0);
}

// ---------------------------------------------------------------------------
// Kernel 0a: W fp32 -> bf16  (3 x 256x256, row-major [o][c] preserved)
// ---------------------------------------------------------------------------
__global__ __launch_bounds__(256) void wcast_kernel(
    const float* __restrict__ Wk, const float* __restrict__ Wq,
    const float* __restrict__ Wv, u16* __restrict__ wbf)
{
  int pj = blockIdx.y;
  const float* W = (pj == 0) ? Wk : ((pj == 1) ? Wq : Wv);
  int idx = blockIdx.x * 1024 + threadIdx.x * 4;
  float4 v = *(const float4*)(W + idx);
  s16x4 pk;
  pk[0] = (short)f2bf(v.x); pk[1] = (short)f2bf(v.y);
  pk[2] = (short)f2bf(v.z); pk[3] = (short)f2bf(v.w);
  *(s16x4*)(wbf + (size_t)pj * 65536 + idx) = pk;
}

// ---------------------------------------------------------------------------
// Kernel 0b: x [b][c][pt] fp32 -> xT [(b,pt)][c] bf16  (64x64 LDS transpose)
// ---------------------------------------------------------------------------
__global__ __launch_bounds__(256, 2) void xcast_kernel(
    const float* __restrict__ x, u16* __restrict__ xT)
{
  int ptt = blockIdx.x;   // 0..1023
  int ct  = blockIdx.y;   // 0..3
  int b   = blockIdx.z;   // 0..3
  __shared__ __align__(16) u16 L[64 * 64];   // [c row][pt col], 128 B pitch
  int tid = threadIdx.x;
#pragma unroll
  for (int i = 0; i < 4; i++) {
    int cl  = i * 16 + (tid >> 4);
    int ptl = (tid & 15) * 4;
    float4 v = *(const float4*)(x + ((size_t)(b * NC + ct * 64 + cl)) * NPT +
                                ptt * 64 + ptl);
    s16x4 pk;
    pk[0] = (short)f2bf(v.x); pk[1] = (short)f2bf(v.y);
    pk[2] = (short)f2bf(v.z); pk[3] = (short)f2bf(v.w);
    *(s16x4*)((char*)L + ((cl * 128 + ptl * 2) ^ swz(cl))) = pk;
  }
  __syncthreads();
#pragma unroll
  for (int i = 0; i < 2; i++) {
    int ptl = i * 32 + (tid >> 3);
    int c8  = (tid & 7) * 8;
    s16x8 v;
#pragma unroll
    for (int j = 0; j < 8; j++) {
      int row = c8 + j;
      v[j] = (short)*(const u16*)((char*)L + ((row * 128 + ptl * 2) ^ swz(row)));
    }
    *(s16x8*)(xT + ((size_t)b * NPT + (size_t)ptt * 64 + ptl) * NC + ct * 64 + c8) = v;
  }
}

// ---------------------------------------------------------------------------
// Kernel 2: V transpose  [bh][p][f] -> [bh][f][p]
// ---------------------------------------------------------------------------
__global__ __launch_bounds__(256, 2) void transpose_kernel(
    const u16* __restrict__ in, u16* __restrict__ outp)
{
  int ft = blockIdx.x;   // 0..31  f-tiles
  int pt = blockIdx.y;   // 0..15  p-tiles
  int slab = blockIdx.z; // 0..31  bh
  __shared__ __align__(16) u16 L[64 * 64];
  int t = threadIdx.x;
  const u16* ip = in + (size_t)slab * NP * NF;
#pragma unroll
  for (int i = 0; i < 2; i++) {
    int pl = i * 32 + (t >> 3);
    int c8 = (t & 7) * 8;
    s16x8 v = *(const s16x8*)(ip + (size_t)(pt * 64 + pl) * NF + ft * 64 + c8);
    *(s16x8*)((char*)L + ((pl * 128 + c8 * 2) ^ swz(pl))) = v;
  }
  __syncthreads();
  u16* op = outp + (size_t)slab * NP * NF;
#pragma unroll
  for (int i = 0; i < 2; i++) {
    int fl = i * 32 + (t >> 3);
    int p8 = (t & 7) * 8;
    s16x8 v;
#pragma unroll
    for (int j2 = 0; j2 < 8; j2++) {
      int row = p8 + j2;
      v[j2] = (short)*(const u16*)((char*)L + ((row * 128 + fl * 2) ^ swz(row)));
    }
    *(s16x8*)(op + (size_t)(ft * 64 + fl) * NP + pt * 64 + p8) = v;
  }
}

// ---------------------------------------------------------------------------
// Kernel 1: fused QKV projection, 16-wave single-buffer m97-style.
// 1024 threads, 256(o) x 256(pt) tile, wave tile 64x64 (acc[4][4] = 64 VGPR
// so 16 waves = 4/SIMD fit under the 128-VGPR launchability bound).
// BK=64, 64 KB LDS single-buffered, plain __syncthreads (compiler-drained).
// T2 swizzle: pre-swizzled gload_lds source + XOR'd ds_read base -> 2-way.
// ---------------------------------------------------------------------------
__global__ __launch_bounds__(1024) void proj1024_kernel(
    const u16* __restrict__ wbf, const u16* __restrict__ xT,
    const float* __restrict__ bk, const float* __restrict__ bq,
    const float* __restrict__ bv, u16* __restrict__ kqv)
{
  __shared__ __align__(16) u16 L[32768];   // A: bytes [0,32768), B: [32768,65536)
  int d0 = blockIdx.x;                  // 0..767
  int b  = blockIdx.y;                  // 0..3
  int xcd = d0 & 7, r = d0 >> 3;        // r: 0..95
  int pj  = r % 3, tch = r / 3;         // tch: 0..31
  int ptile = tch * 8 + xcd;            // 0..255
  const float* bias = (pj == 0) ? bk : ((pj == 1) ? bq : bv);
  u16* outb = kqv + (size_t)pj * KQV_ELEMS;
  const int n0 = ptile * 256;

  const u16* Ag = wbf + (size_t)pj * 65536;            // W [256 o][256 c]
  const u16* Bg = xT + ((size_t)b * NPT + (size_t)n0) * NC;  // [256 pt][256 c]

  const int tid  = threadIdx.x;
  const int lane = tid & 63;
  const int wv   = tid >> 6;            // 0..15
  const int wr = wv >> 2, wc = wv & 3;  // 4M x 4N wave grid, 64x64 each

  // staging: per thread 2 A-granules + 2 B-granules (16 B each).
  // dest (linear) o = wv*1024 + i*16384 + lane*16 ; stored content is the
  // swizzled position: logical col-granule cg = (lane&7) ^ ((lane>>3)&7),
  // row = wv*8 + i*128 + (lane>>3).
  int srow[2], scg;
#pragma unroll
  for (int i = 0; i < 2; i++) srow[i] = wv * 8 + i * 128 + (lane >> 3);
  scg = (lane & 7) ^ ((lane >> 3) & 7);
  const int dbase0 = wv * 1024;             // wave-uniform LDS byte base i=0
  const int dbase1 = wv * 1024 + 16384;     // i=1

  // swizzled ds_read bases: row ra, k-granule g -> byte ra*128 + ((g^(ra&7))<<4)
  const int ra0 = wr * 64 + (lane & 15);
  const int rb0 = wc * 64 + (lane & 15);

  f32x4 acc[4][4];
#pragma unroll
  for (int a = 0; a < 4; a++)
#pragma unroll
    for (int c = 0; c < 4; c++) acc[a][c] = (f32x4){0.f, 0.f, 0.f, 0.f};

  for (int ks = 0; ks < 4; ks++) {
    const int k0 = ks * 64;
    __syncthreads();   // previous tile's reads complete
#pragma unroll
    for (int i = 0; i < 2; i++) {
      GLOAD_LDS16(Ag + (size_t)srow[i] * NC + k0 + scg * 8,
                  L + ((dbase0 + i * 16384) >> 1));
      GLOAD_LDS16(Bg + (size_t)srow[i] * NC + k0 + scg * 8,
                  L + ((32768 + dbase0 + i * 16384) >> 1));
    }
    __syncthreads();   // compiler drains vmcnt before barrier
#pragma unroll
    for (int kk = 0; kk < 2; kk++) {
      bf16x8 af[4], bfr[4];
#pragma unroll
      for (int mf = 0; mf < 4; mf++) {
        int ra = ra0 + mf * 16;
        int g  = kk * 4 + (lane >> 4);
        af[mf] = *(const bf16x8*)((char*)L + ra * 128 + ((g ^ (ra & 7)) << 4));
      }
#pragma unroll
      for (int nf = 0; nf < 4; nf++) {
        int rb = rb0 + nf * 16;
        int g  = kk * 4 + (lane >> 4);
        bfr[nf] = *(const bf16x8*)((char*)L + 32768 + rb * 128 +
                                   ((g ^ (rb & 7)) << 4));
      }
#pragma unroll
      for (int mf = 0; mf < 4; mf++)
#pragma unroll
        for (int nf = 0; nf < 4; nf++)
          acc[mf][nf] = mfma16(af[mf], bfr[nf], acc[mf][nf]);
    }
  }

  // epilogue: +bias, bf16, direct scatter to [bh][p][d*64+t] (ideal WRITE_SIZE)
#pragma unroll
  for (int mf = 0; mf < 4; mf++) {
#pragma unroll
    for (int jj = 0; jj < 4; jj++) {
      int o = wr * 64 + mf * 16 + (lane >> 4) * 4 + jj;
      float bsv = bias[o];
      int hh = o >> 5, dd = o & 31;
#pragma unroll
      for (int nf = 0; nf < 4; nf++) {
        int n = n0 + wc * 64 + nf * 16 + (lane & 15);
        int p = n >> 6, t = n & 63;
        outb[((size_t)(b * NH + hh) * NP + p) * NF + dd * 64 + t] =
            f2bf(acc[mf][nf][jj] + bsv);
      }
    }
  }
}

// ---------------------------------------------------------------------------
// 256x256 deep-pipelined BT GEMM core (BK=32, 4 LDS buffers, 512 threads,
// 8 waves 2Mx4N). Race-free by construction (R5-verified).
// ---------------------------------------------------------------------------
#define STG1(TT, I, OP) do {                                                   \
    const u16* gp_ = (OP ? Bg : Ag) + (size_t)grow[I] * KT + (TT) * 32 + gcol[I]; \
    GLOAD_LDS16(gp_, L + ((((TT) & 3) * 32768 + (OP) * 16384 +                 \
                           ((I) & 1 ? W1 : W0)) >> 1));                        \
  } while (0)

#define FENCE() do {                                                           \
    asm volatile("" ::: "memory");                                             \
    __builtin_amdgcn_sched_barrier(0);                                         \
  } while (0)

#define KBODY(J, WAITASM, DOSTG) do {                                          \
    const int bufb_ = ((J) & 3) * 32768;                                       \
    bf16x8 a_[4], b_[4];                                                       \
    _Pragma("unroll")                                                          \
    for (int mf = 0; mf < 4; mf++)                                             \
      a_[mf] = *(const bf16x8*)((const char*)L + bufb_ + baseA + mf * 1024);   \
    _Pragma("unroll")                                                          \
    for (int nf = 0; nf < 4; nf++)                                             \
      b_[nf] = *(const bf16x8*)((const char*)L + bufb_ + baseB + nf * 1024);   \
    if (DOSTG) { STG1((J) + 3, 0, 0); STG1((J) + 3, 1, 0); }                   \
    __builtin_amdgcn_s_barrier();                                              \
    asm volatile("s_waitcnt lgkmcnt(0)" ::: "memory");                         \
    __builtin_amdgcn_sched_barrier(0);                                         \
    __builtin_amdgcn_s_setprio(1);                                             \
    _Pragma("unroll")                                                          \
    for (int mf = 0; mf < 4; mf++)                                             \
      _Pragma("unroll")                                                        \
      for (int nf = 0; nf < 4; nf++)                                           \
        acc[mf][nf] = mfma16(a_[mf], b_[nf], acc[mf][nf]);                     \
    __builtin_amdgcn_s_setprio(0);                                             \
    __builtin_amdgcn_sched_barrier(0);                                         \
    __builtin_amdgcn_s_barrier();                                              \
    FENCE();                                                                   \
    bf16x8 a2_[4];                                                             \
    _Pragma("unroll")                                                          \
    for (int mf = 0; mf < 4; mf++)                                             \
      a2_[mf] = *(const bf16x8*)((const char*)L + bufb_ + baseA +              \
                                 (4 + mf) * 1024);                             \
    if (DOSTG) { STG1((J) + 3, 2, 1); STG1((J) + 3, 3, 1); }                   \
    __builtin_amdgcn_s_barrier();                                              \
    asm volatile("s_waitcnt lgkmcnt(0)" ::: "memory");                         \
    __builtin_amdgcn_sched_barrier(0);                                         \
    __builtin_amdgcn_s_setprio(1);                                             \
    _Pragma("unroll")                                                          \
    for (int mf = 0; mf < 4; mf++)                                             \
      _Pragma("unroll")                                                        \
      for (int nf = 0; nf < 4; nf++)                                           \
        acc[4 + mf][nf] = mfma16(a2_[mf], b_[nf], acc[4 + mf][nf]);            \
    __builtin_amdgcn_s_setprio(0);                                             \
    __builtin_amdgcn_sched_barrier(0);                                         \
    asm volatile(WAITASM ::: "memory");                                        \
    __builtin_amdgcn_s_barrier();                                              \
    FENCE();                                                                   \
  } while (0)

template <int KT>
__device__ __forceinline__ void core256(const u16* __restrict__ Ag,
                                        const u16* __restrict__ Bg,
                                        u16* L, f32x4 acc[8][4])
{
  constexpr int NKT = KT / 32;
  const int tid  = threadIdx.x;
  const int lane = tid & 63;
  const int wv   = tid >> 6;            // 0..7
  const int wr = wv >> 2, wc = wv & 3;

  // staging source precompute (pre-swizzled): loads 0,1 -> A; 2,3 -> B
  int grow[4], gcol[4];
#pragma unroll
  for (int i = 0; i < 4; i++) {
    int oi   = (tid + (i & 1) * 512) * 16;           // linear byte off in 16KB
    int loff = oi ^ (((oi >> 6) & 3) << 4);          // logical position
    grow[i] = loff >> 6;                             // row 0..255
    gcol[i] = (loff & 63) >> 1;                      // col element 0..31
  }
  const int W0 = wv * 1024;             // wave-uniform LDS byte base, load 0/2
  const int W1 = wv * 1024 + 8192;      // load 1/3

  // swizzled ds_read bases (byte offsets within a buffer)
  const int rowA  = wr * 128 + (lane & 15);
  const int baseA = rowA * 64 + (((lane >> 4) * 16) ^ ((rowA & 3) << 4));
  const int rowB  = wc * 64 + (lane & 15);
  const int baseB = 16384 + rowB * 64 + (((lane >> 4) * 16) ^ ((rowB & 3) << 4));

  // prologue: stage tiles 0,1,2 (12 loads/wave); wait tile 0 (vmcnt(8))
#pragma unroll
  for (int tt = 0; tt < 3; tt++) {
    STG1(tt, 0, 0); STG1(tt, 1, 0); STG1(tt, 2, 1); STG1(tt, 3, 1);
  }
  __builtin_amdgcn_sched_barrier(0);
  asm volatile("s_waitcnt vmcnt(8)" ::: "memory");
  __builtin_amdgcn_s_barrier();
  FENCE();

  for (int j = 0; j < NKT - 3; ++j)
    KBODY(j, "s_waitcnt vmcnt(8)", 1);
  KBODY(NKT - 3, "s_waitcnt vmcnt(4)", 0);
  KBODY(NKT - 2, "s_waitcnt vmcnt(0)", 0);
  KBODY(NKT - 1, "", 0);
}

// S'[q][p] = (sum_f Q[q,f] K[p,f]) * INV_SCALE  (A=Q, B=K)  256x256 tiles
__global__ __launch_bounds__(512, 2) void qk256_kernel(
    const u16* __restrict__ kb, const u16* __restrict__ qb, u16* __restrict__ S)
{
  extern __shared__ u16 L[];            // 128 KB dynamic
  int bid = blockIdx.x;                 // 512 blocks, XCD-swizzled
  int xcd = bid & 7, r = bid >> 3;      // r: 0..63
  int bh  = xcd * 4 + (r >> 4);
  int til = r & 15;
  int mt  = til >> 2, nt = til & 3;

  const u16* Ag = qb + (size_t)bh * NP * NF + (size_t)mt * 256 * NF;
  const u16* Bg = kb + (size_t)bh * NP * NF + (size_t)nt * 256 * NF;

  f32x4 acc[8][4];
#pragma unroll
  for (int a = 0; a < 8; a++)
#pragma unroll
    for (int c = 0; c < 4; c++) acc[a][c] = (f32x4){0.f, 0.f, 0.f, 0.f};

  core256<NF>(Ag, Bg, L, acc);

  const int lane = threadIdx.x & 63, wv = threadIdx.x >> 6;
  const int wr = wv >> 2, wc = wv & 3;
  u16* Sp = S + (size_t)bh * NP * NP;
#pragma unroll
  for (int mf = 0; mf < 8; mf++)
#pragma unroll
    for (int jj = 0; jj < 4; jj++) {
      int m = mt * 256 + wr * 128 + mf * 16 + (lane >> 4) * 4 + jj;   // q
#pragma unroll
      for (int nf = 0; nf < 4; nf++) {
        int n = nt * 256 + wc * 64 + nf * 16 + (lane & 15);           // p
        Sp[(size_t)m * NP + n] = f2bf(acc[mf][nf][jj] * INV_SCALE);
      }
    }
}

// Out[q][f] = sum_p A'[q,p] * Vt[f,p];  write fp32 out[b][h*32+d][q][t]
__global__ __launch_bounds__(512, 2) void av256_kernel(
    const u16* __restrict__ Ab, const u16* __restrict__ Vt, float* __restrict__ out)
{
  extern __shared__ u16 L[];            // 128 KB dynamic
  int bid = blockIdx.x;                 // 1024 blocks, XCD-swizzled
  int xcd = bid & 7, r = bid >> 3;      // r: 0..127
  int bh  = xcd * 4 + (r >> 5);
  int til = r & 31;
  int mt  = til >> 3, ntf = til & 7;

  const u16* Ag = Ab + (size_t)bh * NP * NP + (size_t)mt * 256 * NP;
  const u16* Bg = Vt + (size_t)bh * NF * NP + (size_t)ntf * 256 * NP;

  f32x4 acc[8][4];
#pragma unroll
  for (int a = 0; a < 8; a++)
#pragma unroll
    for (int c = 0; c < 4; c++) acc[a][c] = (f32x4){0.f, 0.f, 0.f, 0.f};

  core256<NP>(Ag, Bg, L, acc);

  const int lane = threadIdx.x & 63, wv = threadIdx.x >> 6;
  const int wr = wv >> 2, wc = wv & 3;
  int b = bh >> 3, h = bh & 7;
#pragma unroll
  for (int mf = 0; mf < 8; mf++)
#pragma unroll
    for (int jj = 0; jj < 4; jj++) {
      int m = mt * 256 + wr * 128 + mf * 16 + (lane >> 4) * 4 + jj;   // q
#pragma unroll
      for (int nf = 0; nf < 4; nf++) {
        int n = ntf * 256 + wc * 64 + nf * 16 + (lane & 15);          // f
        int dd = n >> 6, t = n & 63;
        out[((size_t)(b * NC + h * ND + dd) * NP + m) * NT + t] = acc[mf][nf][jj];
      }
    }
}

// ---------------------------------------------------------------------------
// Column softmax over q. 512 blocks (16 col-blocks x 32 bh), 64 cols/block.
// 256 threads = 8 col-groups(8 cols, 16 B vector loads) x 32 q-chunks(32 rows).
// ---------------------------------------------------------------------------
__global__ __launch_bounds__(256, 2) void softmax_kernel(
    const u16* __restrict__ S, u16* __restrict__ A)
{
  int cb = blockIdx.x;        // 16 blocks of 64 columns
  int bh = blockIdx.y;
  int tid = threadIdx.x;
  int cg  = tid & 7;          // col-group (8 cols)
  int qs  = tid >> 3;         // 0..31
  int col0 = cb * 64 + cg * 8;
  const u16* Sp = S + (size_t)bh * NP * NP + col0;

  float m[8], l[8];
#pragma unroll
  for (int j2 = 0; j2 < 8; j2++) { m[j2] = -1e30f; l[j2] = 0.f; }
  for (int q = qs * 32; q < qs * 32 + 32; q++) {
    s16x8 v = *(const s16x8*)(Sp + (size_t)q * NP);
#pragma unroll
    for (int j2 = 0; j2 < 8; j2++) {
      float f = bf2f((u16)v[j2]);
      float mn = fmaxf(m[j2], f);
      l[j2] = l[j2] * __expf(m[j2] - mn) + __expf(f - mn);
      m[j2] = mn;
    }
  }
  __shared__ float ms[32][64], ls[32][64];
#pragma unroll
  for (int j2 = 0; j2 < 8; j2++) {
    ms[qs][cg * 8 + j2] = m[j2];
    ls[qs][cg * 8 + j2] = l[j2];
  }
  __syncthreads();
  float M[8], Li[8];
#pragma unroll
  for (int j2 = 0; j2 < 8; j2++) {
    int c = cg * 8 + j2;
    float mm = ms[0][c];
#pragma unroll
    for (int k = 1; k < 32; k++) mm = fmaxf(mm, ms[k][c]);
    float ll = 0.f;
#pragma unroll
    for (int k = 0; k < 32; k++) ll += ls[k][c] * __expf(ms[k][c] - mm);
    M[j2] = mm; Li[j2] = 1.f / ll;
  }
  u16* Ap = A + (size_t)bh * NP * NP + col0;
  for (int q = qs * 32; q < qs * 32 + 32; q++) {
    s16x8 v = *(const s16x8*)(Sp + (size_t)q * NP);
    s16x8 o;
#pragma unroll
    for (int j2 = 0; j2 < 8; j2++)
      o[j2] = (short)f2bf(__expf(bf2f((u16)v[j2]) - M[j2]) * Li[j2]);
    *(s16x8*)(Ap + (size_t)q * NP) = o;
  }
}

// ---------------------------------------------------------------------------
extern "C" void kernel_launch(void* const* d_in, const int* in_sizes, int n_in,
                              void* d_out, int out_size, void* d_ws, size_t ws_size,
                              hipStream_t stream)
{
  if (ws_size < 4ull * KQV_ELEMS * sizeof(u16)) return;  // need 537 MB scratch

  const float* x  = (const float*)d_in[0];
  const float* Wk = (const float*)d_in[1];
  const float* bk = (const float*)d_in[2];
  const float* Wq = (const float*)d_in[3];
  const float* bq = (const float*)d_in[4];
  const float* Wv = (const float*)d_in[5];
  const float* bv = (const float*)d_in[6];

  u16* kb = (u16*)d_ws;                    // [bh][p][f]
  u16* qb = kb + KQV_ELEMS;                // [bh][p][f]
  u16* vb = kb + 2 * KQV_ELEMS;            // [bh][p][f]
  u16* vt = kb + 3 * KQV_ELEMS;            // [bh][f][p]

  // d_out head doubles as staging: xT (134 MB) + wbf (0.4 MB) + S (67 MB).
  // All dead before av_kernel rewrites d_out in full.
  u16* xT  = (u16*)d_out;                  // [(b,pt)][c]
  u16* wbf = xT + KQV_ELEMS;               // 3 x 256 x 256
  u16* Sb  = xT + KQV_ELEMS + 262144;      // S'[bh][q][p]
  u16* Ab  = kb;                           // attn A'[bh][q][p], aliases kb

  (void)hipFuncSetAttribute((const void*)qk256_kernel,
                            hipFuncAttributeMaxDynamicSharedMemorySize, 131072);
  (void)hipFuncSetAttribute((const void*)av256_kernel,
                            hipFuncAttributeMaxDynamicSharedMemorySize, 131072);

  wcast_kernel<<<dim3(64, 3), 256, 0, stream>>>(Wk, Wq, Wv, wbf);
  xcast_kernel<<<dim3(1024, 4, 4), 256, 0, stream>>>(x, xT);
  proj1024_kernel<<<dim3(768, 4), 1024, 0, stream>>>(wbf, xT, bk, bq, bv, kb);
  transpose_kernel<<<dim3(32, 16, 32), 256, 0, stream>>>(vb, vt);
  qk256_kernel<<<dim3(512), 512, 131072, stream>>>(kb, qb, Sb);
  softmax_kernel<<<dim3(16, 32), 256, 0, stream>>>(Sb, Ab);
  av256_kernel<<<dim3(1024), 512, 131072, stream>>>(Ab, vt, (float*)d_out);
}

// Round 9
// 675.119 us; speedup vs baseline: 1.0095x; 1.0095x over previous
//
#include <hip/hip_runtime.h>
#include <cstdint>
#include <cstddef>

// Problem constants
#define NB 4
#define NC 256
#define NP 1024
#define NT 64
#define NH 8
#define ND 32
#define NF 2048            // ND*NT, joint contraction dim
#define NPT 65536          // NP*NT
#define KQV_ELEMS 67108864ull   // 32*1024*2048
#define INV_SCALE 0.022097086912079608f  // 1/sqrt(2048)

typedef unsigned short u16;
typedef __bf16 bf16x8 __attribute__((ext_vector_type(8)));
typedef short  s16x8  __attribute__((ext_vector_type(8)));
typedef short  s16x4  __attribute__((ext_vector_type(4)));
typedef float  f32x4  __attribute__((ext_vector_type(4)));

__device__ __forceinline__ u16 f2bf(float f) {
  unsigned u = __builtin_bit_cast(unsigned, f);
  u += 0x7fffu + ((u >> 16) & 1u);        // RNE
  return (u16)(u >> 16);
}
__device__ __forceinline__ float bf2f(u16 h) {
  unsigned u = ((unsigned)h) << 16;
  return __builtin_bit_cast(float, u);
}
// LDS XOR swizzle for transpose staging (byte XOR mask, bits 4..6)
__device__ __forceinline__ int swz(int row) { return ((row ^ (row >> 3)) & 7) << 4; }

#define GLOAD_LDS16(gp, lp) __builtin_amdgcn_global_load_lds( \
    (const __attribute__((address_space(1))) void*)(gp),      \
    (__attribute__((address_space(3))) void*)(lp), 16, 0, 0)

__device__ __forceinline__ f32x4 mfma16(bf16x8 a, bf16x8 b, f32x4 c) {
  return __builtin_amdgcn_mfma_f32_16x16x32_bf16(a, b, c, 0, 0, 0);
}

// ---------------------------------------------------------------------------
// Kernel 0a: W fp32 -> bf16  (3 x 256x256, row-major [o][c] preserved)
// ---------------------------------------------------------------------------
__global__ __launch_bounds__(256) void wcast_kernel(
    const float* __restrict__ Wk, const float* __restrict__ Wq,
    const float* __restrict__ Wv, u16* __restrict__ wbf)
{
  int pj = blockIdx.y;
  const float* W = (pj == 0) ? Wk : ((pj == 1) ? Wq : Wv);
  int idx = blockIdx.x * 1024 + threadIdx.x * 4;
  float4 v = *(const float4*)(W + idx);
  s16x4 pk;
  pk[0] = (short)f2bf(v.x); pk[1] = (short)f2bf(v.y);
  pk[2] = (short)f2bf(v.z); pk[3] = (short)f2bf(v.w);
  *(s16x4*)(wbf + (size_t)pj * 65536 + idx) = pk;
}

// ---------------------------------------------------------------------------
// Kernel 0b: x [b][c][pt] fp32 -> xT [(b,pt)][c] bf16  (64x64 LDS transpose)
// ---------------------------------------------------------------------------
__global__ __launch_bounds__(256, 2) void xcast_kernel(
    const float* __restrict__ x, u16* __restrict__ xT)
{
  int ptt = blockIdx.x;   // 0..1023
  int ct  = blockIdx.y;   // 0..3
  int b   = blockIdx.z;   // 0..3
  __shared__ __align__(16) u16 L[64 * 64];   // [c row][pt col], 128 B pitch
  int tid = threadIdx.x;
#pragma unroll
  for (int i = 0; i < 4; i++) {
    int cl  = i * 16 + (tid >> 4);
    int ptl = (tid & 15) * 4;
    float4 v = *(const float4*)(x + ((size_t)(b * NC + ct * 64 + cl)) * NPT +
                                ptt * 64 + ptl);
    s16x4 pk;
    pk[0] = (short)f2bf(v.x); pk[1] = (short)f2bf(v.y);
    pk[2] = (short)f2bf(v.z); pk[3] = (short)f2bf(v.w);
    *(s16x4*)((char*)L + ((cl * 128 + ptl * 2) ^ swz(cl))) = pk;
  }
  __syncthreads();
#pragma unroll
  for (int i = 0; i < 2; i++) {
    int ptl = i * 32 + (tid >> 3);
    int c8  = (tid & 7) * 8;
    s16x8 v;
#pragma unroll
    for (int j = 0; j < 8; j++) {
      int row = c8 + j;
      v[j] = (short)*(const u16*)((char*)L + ((row * 128 + ptl * 2) ^ swz(row)));
    }
    *(s16x8*)(xT + ((size_t)b * NPT + (size_t)ptt * 64 + ptl) * NC + ct * 64 + c8) = v;
  }
}

// ---------------------------------------------------------------------------
// Kernel 2: V transpose  [bh][p][f] -> [bh][f][p]
// ---------------------------------------------------------------------------
__global__ __launch_bounds__(256, 2) void transpose_kernel(
    const u16* __restrict__ in, u16* __restrict__ outp)
{
  int ft = blockIdx.x;   // 0..31  f-tiles
  int pt = blockIdx.y;   // 0..15  p-tiles
  int slab = blockIdx.z; // 0..31  bh
  __shared__ __align__(16) u16 L[64 * 64];
  int t = threadIdx.x;
  const u16* ip = in + (size_t)slab * NP * NF;
#pragma unroll
  for (int i = 0; i < 2; i++) {
    int pl = i * 32 + (t >> 3);
    int c8 = (t & 7) * 8;
    s16x8 v = *(const s16x8*)(ip + (size_t)(pt * 64 + pl) * NF + ft * 64 + c8);
    *(s16x8*)((char*)L + ((pl * 128 + c8 * 2) ^ swz(pl))) = v;
  }
  __syncthreads();
  u16* op = outp + (size_t)slab * NP * NF;
#pragma unroll
  for (int i = 0; i < 2; i++) {
    int fl = i * 32 + (t >> 3);
    int p8 = (t & 7) * 8;
    s16x8 v;
#pragma unroll
    for (int j2 = 0; j2 < 8; j2++) {
      int row = p8 + j2;
      v[j2] = (short)*(const u16*)((char*)L + ((row * 128 + fl * 2) ^ swz(row)));
    }
    *(s16x8*)(op + (size_t)(ft * 64 + fl) * NP + pt * 64 + p8) = v;
  }
}

// ---------------------------------------------------------------------------
// Kernel 1: fused QKV projection, 16-wave, BK=32 DOUBLE-buffered with counted
// vmcnt(2) lookahead. LDS total still 64 KB (2 bufs x (16K A + 16K B)) so
// occupancy is unchanged vs R8; the pipeline replaces the per-step vmcnt(0)
// drain with a one-step lookahead (R5-proven fence pattern).
// Swizzle: 64 B rows, granule gc' = gc ^ ((row>>1)&3) -> 2-way (free, m136).
// ---------------------------------------------------------------------------
#define PJSTG(TT) do {                                                         \
    GLOAD_LDS16(Ag + (size_t)psrow * NC + (TT) * 32 + psg * 8,                 \
                L + ((((TT) & 1) * 32768 + pdst) >> 1));                       \
    GLOAD_LDS16(Bg + (size_t)psrow * NC + (TT) * 32 + psg * 8,                 \
                L + ((((TT) & 1) * 32768 + 16384 + pdst) >> 1));               \
  } while (0)

#define PJBODY(J, WAITASM, DOSTG) do {                                         \
    if (DOSTG) PJSTG((J) + 1);                                                 \
    __builtin_amdgcn_sched_barrier(0);                                         \
    asm volatile(WAITASM ::: "memory");                                        \
    __builtin_amdgcn_s_barrier();                                              \
    __builtin_amdgcn_sched_barrier(0);                                         \
    {                                                                          \
      const int bb = ((J) & 1) * 32768;                                        \
      bf16x8 af[4], bfr[4];                                                    \
      _Pragma("unroll")                                                        \
      for (int mf = 0; mf < 4; mf++)                                           \
        af[mf] = *(const bf16x8*)((char*)L + bb + baseA + mf * 1024);          \
      _Pragma("unroll")                                                        \
      for (int nf = 0; nf < 4; nf++)                                           \
        bfr[nf] = *(const bf16x8*)((char*)L + bb + 16384 + baseB + nf * 1024); \
      __builtin_amdgcn_s_setprio(1);                                           \
      _Pragma("unroll")                                                        \
      for (int mf = 0; mf < 4; mf++)                                           \
        _Pragma("unroll")                                                      \
        for (int nf = 0; nf < 4; nf++)                                         \
          acc[mf][nf] = mfma16(af[mf], bfr[nf], acc[mf][nf]);                  \
      __builtin_amdgcn_s_setprio(0);                                           \
    }                                                                          \
    __builtin_amdgcn_sched_barrier(0);                                         \
    asm volatile("s_waitcnt lgkmcnt(0)" ::: "memory");                         \
    __builtin_amdgcn_s_barrier();                                              \
    asm volatile("" ::: "memory");                                             \
    __builtin_amdgcn_sched_barrier(0);                                         \
  } while (0)

__global__ __launch_bounds__(1024) void proj1024_kernel(
    const u16* __restrict__ wbf, const u16* __restrict__ xT,
    const float* __restrict__ bk, const float* __restrict__ bq,
    const float* __restrict__ bv, u16* __restrict__ kqv)
{
  __shared__ __align__(16) u16 L[32768];   // 64 KB: buf b: A at b*32768, B at +16384
  int d0 = blockIdx.x;                  // 0..767
  int b  = blockIdx.y;                  // 0..3
  int xcd = d0 & 7, r = d0 >> 3;        // r: 0..95
  int pj  = r % 3, tch = r / 3;         // tch: 0..31
  int ptile = tch * 8 + xcd;            // 0..255
  const float* bias = (pj == 0) ? bk : ((pj == 1) ? bq : bv);
  u16* outb = kqv + (size_t)pj * KQV_ELEMS;
  const int n0 = ptile * 256;

  const u16* Ag = wbf + (size_t)pj * 65536;            // W [256 o][256 c]
  const u16* Bg = xT + ((size_t)b * NPT + (size_t)n0) * NC;  // [256 pt][256 c]

  const int tid  = threadIdx.x;
  const int lane = tid & 63;
  const int wv   = tid >> 6;            // 0..15
  const int wr = wv >> 2, wc = wv & 3;  // 4M x 4N wave grid, 64x64 each

  // staging: 1 A-granule + 1 B-granule (16 B) per thread per K-step.
  // dest linear granule = tid; content = pre-swizzled source granule.
  const int psrow = tid >> 2;                      // row 0..255
  const int psg   = (lane & 3) ^ ((lane >> 3) & 3);// source k-granule
  const int pdst  = wv * 1024;                     // wave-uniform dest byte base

  // swizzled ds_read bases: row ra, k-granule gk=lane>>4 ->
  // byte = ra*64 + ((gk ^ ((ra>>1)&3))<<4); mf*16 rows preserve the XOR term.
  const int ra0 = wr * 64 + (lane & 15);
  const int rb0 = wc * 64 + (lane & 15);
  const int gk  = lane >> 4;
  const int baseA = ra0 * 64 + ((gk ^ ((ra0 >> 1) & 3)) << 4);
  const int baseB = rb0 * 64 + ((gk ^ ((rb0 >> 1) & 3)) << 4);

  f32x4 acc[4][4];
#pragma unroll
  for (int a = 0; a < 4; a++)
#pragma unroll
    for (int c = 0; c < 4; c++) acc[a][c] = (f32x4){0.f, 0.f, 0.f, 0.f};

  // prologue: stage tile 0 into buf0
  PJSTG(0);
  __builtin_amdgcn_sched_barrier(0);

  PJBODY(0, "s_waitcnt vmcnt(2)", 1);
  PJBODY(1, "s_waitcnt vmcnt(2)", 1);
  PJBODY(2, "s_waitcnt vmcnt(2)", 1);
  PJBODY(3, "s_waitcnt vmcnt(2)", 1);
  PJBODY(4, "s_waitcnt vmcnt(2)", 1);
  PJBODY(5, "s_waitcnt vmcnt(2)", 1);
  PJBODY(6, "s_waitcnt vmcnt(2)", 1);
  PJBODY(7, "s_waitcnt vmcnt(0)", 0);

  // epilogue: +bias, bf16, direct scatter to [bh][p][d*64+t] (ideal WRITE_SIZE)
#pragma unroll
  for (int mf = 0; mf < 4; mf++) {
#pragma unroll
    for (int jj = 0; jj < 4; jj++) {
      int o = wr * 64 + mf * 16 + (lane >> 4) * 4 + jj;
      float bsv = bias[o];
      int hh = o >> 5, dd = o & 31;
#pragma unroll
      for (int nf = 0; nf < 4; nf++) {
        int n = n0 + wc * 64 + nf * 16 + (lane & 15);
        int p = n >> 6, t = n & 63;
        outb[((size_t)(b * NH + hh) * NP + p) * NF + dd * 64 + t] =
            f2bf(acc[mf][nf][jj] + bsv);
      }
    }
  }
}

// ---------------------------------------------------------------------------
// 256x256 deep-pipelined BT GEMM core (BK=32, 4 LDS buffers, 512 threads,
// 8 waves 2Mx4N). Race-free by construction (R5-verified).
// ---------------------------------------------------------------------------
#define STG1(TT, I, OP) do {                                                   \
    const u16* gp_ = (OP ? Bg : Ag) + (size_t)grow[I] * KT + (TT) * 32 + gcol[I]; \
    GLOAD_LDS16(gp_, L + ((((TT) & 3) * 32768 + (OP) * 16384 +                 \
                           ((I) & 1 ? W1 : W0)) >> 1));                        \
  } while (0)

#define FENCE() do {                                                           \
    asm volatile("" ::: "memory");                                             \
    __builtin_amdgcn_sched_barrier(0);                                         \
  } while (0)

#define KBODY(J, WAITASM, DOSTG) do {                                          \
    const int bufb_ = ((J) & 3) * 32768;                                       \
    bf16x8 a_[4], b_[4];                                                       \
    _Pragma("unroll")                                                          \
    for (int mf = 0; mf < 4; mf++)                                             \
      a_[mf] = *(const bf16x8*)((const char*)L + bufb_ + baseA + mf * 1024);   \
    _Pragma("unroll")                                                          \
    for (int nf = 0; nf < 4; nf++)                                             \
      b_[nf] = *(const bf16x8*)((const char*)L + bufb_ + baseB + nf * 1024);   \
    if (DOSTG) { STG1((J) + 3, 0, 0); STG1((J) + 3, 1, 0); }                   \
    __builtin_amdgcn_s_barrier();                                              \
    asm volatile("s_waitcnt lgkmcnt(0)" ::: "memory");                         \
    __builtin_amdgcn_sched_barrier(0);                                         \
    __builtin_amdgcn_s_setprio(1);                                             \
    _Pragma("unroll")                                                          \
    for (int mf = 0; mf < 4; mf++)                                             \
      _Pragma("unroll")                                                        \
      for (int nf = 0; nf < 4; nf++)                                           \
        acc[mf][nf] = mfma16(a_[mf], b_[nf], acc[mf][nf]);                     \
    __builtin_amdgcn_s_setprio(0);                                             \
    __builtin_amdgcn_sched_barrier(0);                                         \
    __builtin_amdgcn_s_barrier();                                              \
    FENCE();                                                                   \
    bf16x8 a2_[4];                                                             \
    _Pragma("unroll")                                                          \
    for (int mf = 0; mf < 4; mf++)                                             \
      a2_[mf] = *(const bf16x8*)((const char*)L + bufb_ + baseA +              \
                                 (4 + mf) * 1024);                             \
    if (DOSTG) { STG1((J) + 3, 2, 1); STG1((J) + 3, 3, 1); }                   \
    __builtin_amdgcn_s_barrier();                                              \
    asm volatile("s_waitcnt lgkmcnt(0)" ::: "memory");                         \
    __builtin_amdgcn_sched_barrier(0);                                         \
    __builtin_amdgcn_s_setprio(1);                                             \
    _Pragma("unroll")                                                          \
    for (int mf = 0; mf < 4; mf++)                                             \
      _Pragma("unroll")                                                        \
      for (int nf = 0; nf < 4; nf++)                                           \
        acc[4 + mf][nf] = mfma16(a2_[mf], b_[nf], acc[4 + mf][nf]);            \
    __builtin_amdgcn_s_setprio(0);                                             \
    __builtin_amdgcn_sched_barrier(0);                                         \
    asm volatile(WAITASM ::: "memory");                                        \
    __builtin_amdgcn_s_barrier();                                              \
    FENCE();                                                                   \
  } while (0)

template <int KT>
__device__ __forceinline__ void core256(const u16* __restrict__ Ag,
                                        const u16* __restrict__ Bg,
                                        u16* L, f32x4 acc[8][4])
{
  constexpr int NKT = KT / 32;
  const int tid  = threadIdx.x;
  const int lane = tid & 63;
  const int wv   = tid >> 6;            // 0..7
  const int wr = wv >> 2, wc = wv & 3;

  // staging source precompute (pre-swizzled): loads 0,1 -> A; 2,3 -> B
  int grow[4], gcol[4];
#pragma unroll
  for (int i = 0; i < 4; i++) {
    int oi   = (tid + (i & 1) * 512) * 16;           // linear byte off in 16KB
    int loff = oi ^ (((oi >> 6) & 3) << 4);          // logical position
    grow[i] = loff >> 6;                             // row 0..255
    gcol[i] = (loff & 63) >> 1;                      // col element 0..31
  }
  const int W0 = wv * 1024;             // wave-uniform LDS byte base, load 0/2
  const int W1 = wv * 1024 + 8192;      // load 1/3

  // swizzled ds_read bases (byte offsets within a buffer)
  const int rowA  = wr * 128 + (lane & 15);
  const int baseA = rowA * 64 + (((lane >> 4) * 16) ^ ((rowA & 3) << 4));
  const int rowB  = wc * 64 + (lane & 15);
  const int baseB = 16384 + rowB * 64 + (((lane >> 4) * 16) ^ ((rowB & 3) << 4));

  // prologue: stage tiles 0,1,2 (12 loads/wave); wait tile 0 (vmcnt(8))
#pragma unroll
  for (int tt = 0; tt < 3; tt++) {
    STG1(tt, 0, 0); STG1(tt, 1, 0); STG1(tt, 2, 1); STG1(tt, 3, 1);
  }
  __builtin_amdgcn_sched_barrier(0);
  asm volatile("s_waitcnt vmcnt(8)" ::: "memory");
  __builtin_amdgcn_s_barrier();
  FENCE();

  for (int j = 0; j < NKT - 3; ++j)
    KBODY(j, "s_waitcnt vmcnt(8)", 1);
  KBODY(NKT - 3, "s_waitcnt vmcnt(4)", 0);
  KBODY(NKT - 2, "s_waitcnt vmcnt(0)", 0);
  KBODY(NKT - 1, "", 0);
}

// S'[q][p] = (sum_f Q[q,f] K[p,f]) * INV_SCALE  (A=Q, B=K)  256x256 tiles
__global__ __launch_bounds__(512, 2) void qk256_kernel(
    const u16* __restrict__ kb, const u16* __restrict__ qb, u16* __restrict__ S)
{
  extern __shared__ u16 L[];            // 128 KB dynamic
  int bid = blockIdx.x;                 // 512 blocks, XCD-swizzled
  int xcd = bid & 7, r = bid >> 3;      // r: 0..63
  int bh  = xcd * 4 + (r >> 4);
  int til = r & 15;
  int mt  = til >> 2, nt = til & 3;

  const u16* Ag = qb + (size_t)bh * NP * NF + (size_t)mt * 256 * NF;
  const u16* Bg = kb + (size_t)bh * NP * NF + (size_t)nt * 256 * NF;

  f32x4 acc[8][4];
#pragma unroll
  for (int a = 0; a < 8; a++)
#pragma unroll
    for (int c = 0; c < 4; c++) acc[a][c] = (f32x4){0.f, 0.f, 0.f, 0.f};

  core256<NF>(Ag, Bg, L, acc);

  const int lane = threadIdx.x & 63, wv = threadIdx.x >> 6;
  const int wr = wv >> 2, wc = wv & 3;
  u16* Sp = S + (size_t)bh * NP * NP;
#pragma unroll
  for (int mf = 0; mf < 8; mf++)
#pragma unroll
    for (int jj = 0; jj < 4; jj++) {
      int m = mt * 256 + wr * 128 + mf * 16 + (lane >> 4) * 4 + jj;   // q
#pragma unroll
      for (int nf = 0; nf < 4; nf++) {
        int n = nt * 256 + wc * 64 + nf * 16 + (lane & 15);           // p
        Sp[(size_t)m * NP + n] = f2bf(acc[mf][nf][jj] * INV_SCALE);
      }
    }
}

// Out[q][f] = sum_p A'[q,p] * Vt[f,p];  write fp32 out[b][h*32+d][q][t]
__global__ __launch_bounds__(512, 2) void av256_kernel(
    const u16* __restrict__ Ab, const u16* __restrict__ Vt, float* __restrict__ out)
{
  extern __shared__ u16 L[];            // 128 KB dynamic
  int bid = blockIdx.x;                 // 1024 blocks, XCD-swizzled
  int xcd = bid & 7, r = bid >> 3;      // r: 0..127
  int bh  = xcd * 4 + (r >> 5);
  int til = r & 31;
  int mt  = til >> 3, ntf = til & 7;

  const u16* Ag = Ab + (size_t)bh * NP * NP + (size_t)mt * 256 * NP;
  const u16* Bg = Vt + (size_t)bh * NF * NP + (size_t)ntf * 256 * NP;

  f32x4 acc[8][4];
#pragma unroll
  for (int a = 0; a < 8; a++)
#pragma unroll
    for (int c = 0; c < 4; c++) acc[a][c] = (f32x4){0.f, 0.f, 0.f, 0.f};

  core256<NP>(Ag, Bg, L, acc);

  const int lane = threadIdx.x & 63, wv = threadIdx.x >> 6;
  const int wr = wv >> 2, wc = wv & 3;
  int b = bh >> 3, h = bh & 7;
#pragma unroll
  for (int mf = 0; mf < 8; mf++)
#pragma unroll
    for (int jj = 0; jj < 4; jj++) {
      int m = mt * 256 + wr * 128 + mf * 16 + (lane >> 4) * 4 + jj;   // q
#pragma unroll
      for (int nf = 0; nf < 4; nf++) {
        int n = ntf * 256 + wc * 64 + nf * 16 + (lane & 15);          // f
        int dd = n >> 6, t = n & 63;
        out[((size_t)(b * NC + h * ND + dd) * NP + m) * NT + t] = acc[mf][nf][jj];
      }
    }
}

// ---------------------------------------------------------------------------
// Column softmax over q. 512 blocks (16 col-blocks x 32 bh), 64 cols/block.
// 256 threads = 8 col-groups(8 cols, 16 B vector loads) x 32 q-chunks(32 rows).
// ---------------------------------------------------------------------------
__global__ __launch_bounds__(256, 2) void softmax_kernel(
    const u16* __restrict__ S, u16* __restrict__ A)
{
  int cb = blockIdx.x;        // 16 blocks of 64 columns
  int bh = blockIdx.y;
  int tid = threadIdx.x;
  int cg  = tid & 7;          // col-group (8 cols)
  int qs  = tid >> 3;         // 0..31
  int col0 = cb * 64 + cg * 8;
  const u16* Sp = S + (size_t)bh * NP * NP + col0;

  float m[8], l[8];
#pragma unroll
  for (int j2 = 0; j2 < 8; j2++) { m[j2] = -1e30f; l[j2] = 0.f; }
  for (int q = qs * 32; q < qs * 32 + 32; q++) {
    s16x8 v = *(const s16x8*)(Sp + (size_t)q * NP);
#pragma unroll
    for (int j2 = 0; j2 < 8; j2++) {
      float f = bf2f((u16)v[j2]);
      float mn = fmaxf(m[j2], f);
      l[j2] = l[j2] * __expf(m[j2] - mn) + __expf(f - mn);
      m[j2] = mn;
    }
  }
  __shared__ float ms[32][64], ls[32][64];
#pragma unroll
  for (int j2 = 0; j2 < 8; j2++) {
    ms[qs][cg * 8 + j2] = m[j2];
    ls[qs][cg * 8 + j2] = l[j2];
  }
  __syncthreads();
  float M[8], Li[8];
#pragma unroll
  for (int j2 = 0; j2 < 8; j2++) {
    int c = cg * 8 + j2;
    float mm = ms[0][c];
#pragma unroll
    for (int k = 1; k < 32; k++) mm = fmaxf(mm, ms[k][c]);
    float ll = 0.f;
#pragma unroll
    for (int k = 0; k < 32; k++) ll += ls[k][c] * __expf(ms[k][c] - mm);
    M[j2] = mm; Li[j2] = 1.f / ll;
  }
  u16* Ap = A + (size_t)bh * NP * NP + col0;
  for (int q = qs * 32; q < qs * 32 + 32; q++) {
    s16x8 v = *(const s16x8*)(Sp + (size_t)q * NP);
    s16x8 o;
#pragma unroll
    for (int j2 = 0; j2 < 8; j2++)
      o[j2] = (short)f2bf(__expf(bf2f((u16)v[j2]) - M[j2]) * Li[j2]);
    *(s16x8*)(Ap + (size_t)q * NP) = o;
  }
}

// ---------------------------------------------------------------------------
extern "C" void kernel_launch(void* const* d_in, const int* in_sizes, int n_in,
                              void* d_out, int out_size, void* d_ws, size_t ws_size,
                              hipStream_t stream)
{
  if (ws_size < 4ull * KQV_ELEMS * sizeof(u16)) return;  // need 537 MB scratch

  const float* x  = (const float*)d_in[0];
  const float* Wk = (const float*)d_in[1];
  const float* bk = (const float*)d_in[2];
  const float* Wq = (const float*)d_in[3];
  const float* bq = (const float*)d_in[4];
  const float* Wv = (const float*)d_in[5];
  const float* bv = (const float*)d_in[6];

  u16* kb = (u16*)d_ws;                    // [bh][p][f]
  u16* qb = kb + KQV_ELEMS;                // [bh][p][f]
  u16* vb = kb + 2 * KQV_ELEMS;            // [bh][p][f]
  u16* vt = kb + 3 * KQV_ELEMS;            // [bh][f][p]

  // d_out head doubles as staging: xT (134 MB) + wbf (0.4 MB) + S (67 MB).
  // All dead before av_kernel rewrites d_out in full.
  u16* xT  = (u16*)d_out;                  // [(b,pt)][c]
  u16* wbf = xT + KQV_ELEMS;               // 3 x 256 x 256
  u16* Sb  = xT + KQV_ELEMS + 262144;      // S'[bh][q][p]
  u16* Ab  = kb;                           // attn A'[bh][q][p], aliases kb

  (void)hipFuncSetAttribute((const void*)qk256_kernel,
                            hipFuncAttributeMaxDynamicSharedMemorySize, 131072);
  (void)hipFuncSetAttribute((const void*)av256_kernel,
                            hipFuncAttributeMaxDynamicSharedMemorySize, 131072);

  wcast_kernel<<<dim3(64, 3), 256, 0, stream>>>(Wk, Wq, Wv, wbf);
  xcast_kernel<<<dim3(1024, 4, 4), 256, 0, stream>>>(x, xT);
  proj1024_kernel<<<dim3(768, 4), 1024, 0, stream>>>(wbf, xT, bk, bq, bv, kb);
  transpose_kernel<<<dim3(32, 16, 32), 256, 0, stream>>>(vb, vt);
  qk256_kernel<<<dim3(512), 512, 131072, stream>>>(kb, qb, Sb);
  softmax_kernel<<<dim3(16, 32), 256, 0, stream>>>(Sb, Ab);
  av256_kernel<<<dim3(1024), 512, 131072, stream>>>(Ab, vt, (float*)d_out);
}

// Round 10
// 635.625 us; speedup vs baseline: 1.0722x; 1.0621x over previous
//
#include <hip/hip_runtime.h>
#include <cstdint>
#include <cstddef>

// Problem constants
#define NB 4
#define NC 256
#define NP 1024
#define NT 64
#define NH 8
#define ND 32
#define NF 2048            // ND*NT, joint contraction dim
#define NPT 65536          // NP*NT
#define KQV_ELEMS 67108864ull   // 32*1024*2048
#define INV_SCALE 0.022097086912079608f  // 1/sqrt(2048)
#define MHAT 4.0f          // global softmax shift: exp(S'-4) safe, S' max ~1.8

typedef unsigned short u16;
typedef __bf16 bf16x8 __attribute__((ext_vector_type(8)));
typedef short  s16x8  __attribute__((ext_vector_type(8)));
typedef short  s16x4  __attribute__((ext_vector_type(4)));
typedef float  f32x4  __attribute__((ext_vector_type(4)));

__device__ __forceinline__ u16 f2bf(float f) {
  unsigned u = __builtin_bit_cast(unsigned, f);
  u += 0x7fffu + ((u >> 16) & 1u);        // RNE
  return (u16)(u >> 16);
}
__device__ __forceinline__ float bf2f(u16 h) {
  unsigned u = ((unsigned)h) << 16;
  return __builtin_bit_cast(float, u);
}
// LDS XOR swizzle for transpose staging (byte XOR mask, bits 4..6)
__device__ __forceinline__ int swz(int row) { return ((row ^ (row >> 3)) & 7) << 4; }

#define GLOAD_LDS16(gp, lp) __builtin_amdgcn_global_load_lds( \
    (const __attribute__((address_space(1))) void*)(gp),      \
    (__attribute__((address_space(3))) void*)(lp), 16, 0, 0)

__device__ __forceinline__ f32x4 mfma16(bf16x8 a, bf16x8 b, f32x4 c) {
  return __builtin_amdgcn_mfma_f32_16x16x32_bf16(a, b, c, 0, 0, 0);
}

// ---------------------------------------------------------------------------
// Kernel 0a: W fp32 -> bf16  (3 x 256x256, row-major [o][c] preserved)
// ---------------------------------------------------------------------------
__global__ __launch_bounds__(256) void wcast_kernel(
    const float* __restrict__ Wk, const float* __restrict__ Wq,
    const float* __restrict__ Wv, u16* __restrict__ wbf)
{
  int pj = blockIdx.y;
  const float* W = (pj == 0) ? Wk : ((pj == 1) ? Wq : Wv);
  int idx = blockIdx.x * 1024 + threadIdx.x * 4;
  float4 v = *(const float4*)(W + idx);
  s16x4 pk;
  pk[0] = (short)f2bf(v.x); pk[1] = (short)f2bf(v.y);
  pk[2] = (short)f2bf(v.z); pk[3] = (short)f2bf(v.w);
  *(s16x4*)(wbf + (size_t)pj * 65536 + idx) = pk;
}

// ---------------------------------------------------------------------------
// Kernel 0b: x [b][c][pt] fp32 -> xT [(b,pt)][c] bf16  (64x64 LDS transpose)
// ---------------------------------------------------------------------------
__global__ __launch_bounds__(256, 2) void xcast_kernel(
    const float* __restrict__ x, u16* __restrict__ xT)
{
  int ptt = blockIdx.x;   // 0..1023
  int ct  = blockIdx.y;   // 0..3
  int b   = blockIdx.z;   // 0..3
  __shared__ __align__(16) u16 L[64 * 64];   // [c row][pt col], 128 B pitch
  int tid = threadIdx.x;
#pragma unroll
  for (int i = 0; i < 4; i++) {
    int cl  = i * 16 + (tid >> 4);
    int ptl = (tid & 15) * 4;
    float4 v = *(const float4*)(x + ((size_t)(b * NC + ct * 64 + cl)) * NPT +
                                ptt * 64 + ptl);
    s16x4 pk;
    pk[0] = (short)f2bf(v.x); pk[1] = (short)f2bf(v.y);
    pk[2] = (short)f2bf(v.z); pk[3] = (short)f2bf(v.w);
    *(s16x4*)((char*)L + ((cl * 128 + ptl * 2) ^ swz(cl))) = pk;
  }
  __syncthreads();
#pragma unroll
  for (int i = 0; i < 2; i++) {
    int ptl = i * 32 + (tid >> 3);
    int c8  = (tid & 7) * 8;
    s16x8 v;
#pragma unroll
    for (int j = 0; j < 8; j++) {
      int row = c8 + j;
      v[j] = (short)*(const u16*)((char*)L + ((row * 128 + ptl * 2) ^ swz(row)));
    }
    *(s16x8*)(xT + ((size_t)b * NPT + (size_t)ptt * 64 + ptl) * NC + ct * 64 + c8) = v;
  }
}

// ---------------------------------------------------------------------------
// Kernel 2: V transpose  [bh][p][f] -> [bh][f][p], fused * sscale[bh][p]
// (sscale = 1/L~ folds the softmax denominator into V for free)
// ---------------------------------------------------------------------------
__global__ __launch_bounds__(256, 2) void transpose_kernel(
    const u16* __restrict__ in, u16* __restrict__ outp,
    const float* __restrict__ sscale)
{
  int ft = blockIdx.x;   // 0..31  f-tiles
  int pt = blockIdx.y;   // 0..15  p-tiles
  int slab = blockIdx.z; // 0..31  bh
  __shared__ __align__(16) u16 L[64 * 64];
  int t = threadIdx.x;
  const u16* ip = in + (size_t)slab * NP * NF;
#pragma unroll
  for (int i = 0; i < 2; i++) {
    int pl = i * 32 + (t >> 3);
    int c8 = (t & 7) * 8;
    s16x8 v = *(const s16x8*)(ip + (size_t)(pt * 64 + pl) * NF + ft * 64 + c8);
    *(s16x8*)((char*)L + ((pl * 128 + c8 * 2) ^ swz(pl))) = v;
  }
  __syncthreads();
  u16* op = outp + (size_t)slab * NP * NF;
#pragma unroll
  for (int i = 0; i < 2; i++) {
    int fl = i * 32 + (t >> 3);
    int p8 = (t & 7) * 8;
    const float* sc = sscale + slab * 1024 + pt * 64 + p8;
    s16x8 v;
#pragma unroll
    for (int j2 = 0; j2 < 8; j2++) {
      int row = p8 + j2;
      u16 raw = *(const u16*)((char*)L + ((row * 128 + fl * 2) ^ swz(row)));
      v[j2] = (short)f2bf(bf2f(raw) * sc[j2]);
    }
    *(s16x8*)(op + (size_t)(ft * 64 + fl) * NP + pt * 64 + p8) = v;
  }
}

// ---------------------------------------------------------------------------
// Kernel 1: fused QKV projection, 16-wave, BK=32 double-buffered (R9 form)
// ---------------------------------------------------------------------------
#define PJSTG(TT) do {                                                         \
    GLOAD_LDS16(Ag + (size_t)psrow * NC + (TT) * 32 + psg * 8,                 \
                L + ((((TT) & 1) * 32768 + pdst) >> 1));                       \
    GLOAD_LDS16(Bg + (size_t)psrow * NC + (TT) * 32 + psg * 8,                 \
                L + ((((TT) & 1) * 32768 + 16384 + pdst) >> 1));               \
  } while (0)

#define PJBODY(J, WAITASM, DOSTG) do {                                         \
    if (DOSTG) PJSTG((J) + 1);                                                 \
    __builtin_amdgcn_sched_barrier(0);                                         \
    asm volatile(WAITASM ::: "memory");                                        \
    __builtin_amdgcn_s_barrier();                                              \
    __builtin_amdgcn_sched_barrier(0);                                         \
    {                                                                          \
      const int bb = ((J) & 1) * 32768;                                        \
      bf16x8 af[4], bfr[4];                                                    \
      _Pragma("unroll")                                                        \
      for (int mf = 0; mf < 4; mf++)                                           \
        af[mf] = *(const bf16x8*)((char*)L + bb + baseA + mf * 1024);          \
      _Pragma("unroll")                                                        \
      for (int nf = 0; nf < 4; nf++)                                           \
        bfr[nf] = *(const bf16x8*)((char*)L + bb + 16384 + baseB + nf * 1024); \
      __builtin_amdgcn_s_setprio(1);                                           \
      _Pragma("unroll")                                                        \
      for (int mf = 0; mf < 4; mf++)                                           \
        _Pragma("unroll")                                                      \
        for (int nf = 0; nf < 4; nf++)                                         \
          acc[mf][nf] = mfma16(af[mf], bfr[nf], acc[mf][nf]);                  \
      __builtin_amdgcn_s_setprio(0);                                           \
    }                                                                          \
    __builtin_amdgcn_sched_barrier(0);                                         \
    asm volatile("s_waitcnt lgkmcnt(0)" ::: "memory");                         \
    __builtin_amdgcn_s_barrier();                                              \
    asm volatile("" ::: "memory");                                             \
    __builtin_amdgcn_sched_barrier(0);                                         \
  } while (0)

__global__ __launch_bounds__(1024) void proj1024_kernel(
    const u16* __restrict__ wbf, const u16* __restrict__ xT,
    const float* __restrict__ bk, const float* __restrict__ bq,
    const float* __restrict__ bv, u16* __restrict__ kqv)
{
  __shared__ __align__(16) u16 L[32768];   // 64 KB: buf b: A at b*32768, B at +16384
  int d0 = blockIdx.x;                  // 0..767
  int b  = blockIdx.y;                  // 0..3
  int xcd = d0 & 7, r = d0 >> 3;        // r: 0..95
  int pj  = r % 3, tch = r / 3;         // tch: 0..31
  int ptile = tch * 8 + xcd;            // 0..255
  const float* bias = (pj == 0) ? bk : ((pj == 1) ? bq : bv);
  u16* outb = kqv + (size_t)pj * KQV_ELEMS;
  const int n0 = ptile * 256;

  const u16* Ag = wbf + (size_t)pj * 65536;            // W [256 o][256 c]
  const u16* Bg = xT + ((size_t)b * NPT + (size_t)n0) * NC;  // [256 pt][256 c]

  const int tid  = threadIdx.x;
  const int lane = tid & 63;
  const int wv   = tid >> 6;            // 0..15
  const int wr = wv >> 2, wc = wv & 3;  // 4M x 4N wave grid, 64x64 each

  const int psrow = tid >> 2;                      // row 0..255
  const int psg   = (lane & 3) ^ ((lane >> 3) & 3);// source k-granule
  const int pdst  = wv * 1024;                     // wave-uniform dest byte base

  const int ra0 = wr * 64 + (lane & 15);
  const int rb0 = wc * 64 + (lane & 15);
  const int gk  = lane >> 4;
  const int baseA = ra0 * 64 + ((gk ^ ((ra0 >> 1) & 3)) << 4);
  const int baseB = rb0 * 64 + ((gk ^ ((rb0 >> 1) & 3)) << 4);

  f32x4 acc[4][4];
#pragma unroll
  for (int a = 0; a < 4; a++)
#pragma unroll
    for (int c = 0; c < 4; c++) acc[a][c] = (f32x4){0.f, 0.f, 0.f, 0.f};

  PJSTG(0);
  __builtin_amdgcn_sched_barrier(0);

  PJBODY(0, "s_waitcnt vmcnt(2)", 1);
  PJBODY(1, "s_waitcnt vmcnt(2)", 1);
  PJBODY(2, "s_waitcnt vmcnt(2)", 1);
  PJBODY(3, "s_waitcnt vmcnt(2)", 1);
  PJBODY(4, "s_waitcnt vmcnt(2)", 1);
  PJBODY(5, "s_waitcnt vmcnt(2)", 1);
  PJBODY(6, "s_waitcnt vmcnt(2)", 1);
  PJBODY(7, "s_waitcnt vmcnt(0)", 0);

  // epilogue: +bias, bf16, direct scatter to [bh][p][d*64+t]
#pragma unroll
  for (int mf = 0; mf < 4; mf++) {
#pragma unroll
    for (int jj = 0; jj < 4; jj++) {
      int o = wr * 64 + mf * 16 + (lane >> 4) * 4 + jj;
      float bsv = bias[o];
      int hh = o >> 5, dd = o & 31;
#pragma unroll
      for (int nf = 0; nf < 4; nf++) {
        int n = n0 + wc * 64 + nf * 16 + (lane & 15);
        int p = n >> 6, t = n & 63;
        outb[((size_t)(b * NH + hh) * NP + p) * NF + dd * 64 + t] =
            f2bf(acc[mf][nf][jj] + bsv);
      }
    }
  }
}

// ---------------------------------------------------------------------------
// 256x256 deep-pipelined BT GEMM core (BK=32, 4 LDS buffers, 512 threads).
// R10: swizzle fixed 4-way -> 2-way: XOR granule with (row>>1)&3 (R9-proj-
// proven pattern, SQ_LDS_BANK_CONFLICT=0). Involution on both sides.
// ---------------------------------------------------------------------------
#define STG1(TT, I, OP) do {                                                   \
    const u16* gp_ = (OP ? Bg : Ag) + (size_t)grow[I] * KT + (TT) * 32 + gcol[I]; \
    GLOAD_LDS16(gp_, L + ((((TT) & 3) * 32768 + (OP) * 16384 +                 \
                           ((I) & 1 ? W1 : W0)) >> 1));                        \
  } while (0)

#define FENCE() do {                                                           \
    asm volatile("" ::: "memory");                                             \
    __builtin_amdgcn_sched_barrier(0);                                         \
  } while (0)

#define KBODY(J, WAITASM, DOSTG) do {                                          \
    const int bufb_ = ((J) & 3) * 32768;                                       \
    bf16x8 a_[4], b_[4];                                                       \
    _Pragma("unroll")                                                          \
    for (int mf = 0; mf < 4; mf++)                                             \
      a_[mf] = *(const bf16x8*)((const char*)L + bufb_ + baseA + mf * 1024);   \
    _Pragma("unroll")                                                          \
    for (int nf = 0; nf < 4; nf++)                                             \
      b_[nf] = *(const bf16x8*)((const char*)L + bufb_ + baseB + nf * 1024);   \
    if (DOSTG) { STG1((J) + 3, 0, 0); STG1((J) + 3, 1, 0); }                   \
    __builtin_amdgcn_s_barrier();                                              \
    asm volatile("s_waitcnt lgkmcnt(0)" ::: "memory");                         \
    __builtin_amdgcn_sched_barrier(0);                                         \
    __builtin_amdgcn_s_setprio(1);                                             \
    _Pragma("unroll")                                                          \
    for (int mf = 0; mf < 4; mf++)                                             \
      _Pragma("unroll")                                                        \
      for (int nf = 0; nf < 4; nf++)                                           \
        acc[mf][nf] = mfma16(a_[mf], b_[nf], acc[mf][nf]);                     \
    __builtin_amdgcn_s_setprio(0);                                             \
    __builtin_amdgcn_sched_barrier(0);                                         \
    __builtin_amdgcn_s_barrier();                                              \
    FENCE();                                                                   \
    bf16x8 a2_[4];                                                             \
    _Pragma("unroll")                                                          \
    for (int mf = 0; mf < 4; mf++)                                             \
      a2_[mf] = *(const bf16x8*)((const char*)L + bufb_ + baseA +              \
                                 (4 + mf) * 1024);                             \
    if (DOSTG) { STG1((J) + 3, 2, 1); STG1((J) + 3, 3, 1); }                   \
    __builtin_amdgcn_s_barrier();                                              \
    asm volatile("s_waitcnt lgkmcnt(0)" ::: "memory");                         \
    __builtin_amdgcn_sched_barrier(0);                                         \
    __builtin_amdgcn_s_setprio(1);                                             \
    _Pragma("unroll")                                                          \
    for (int mf = 0; mf < 4; mf++)                                             \
      _Pragma("unroll")                                                        \
      for (int nf = 0; nf < 4; nf++)                                           \
        acc[4 + mf][nf] = mfma16(a2_[mf], b_[nf], acc[4 + mf][nf]);            \
    __builtin_amdgcn_s_setprio(0);                                             \
    __builtin_amdgcn_sched_barrier(0);                                         \
    asm volatile(WAITASM ::: "memory");                                        \
    __builtin_amdgcn_s_barrier();                                              \
    FENCE();                                                                   \
  } while (0)

template <int KT>
__device__ __forceinline__ void core256(const u16* __restrict__ Ag,
                                        const u16* __restrict__ Bg,
                                        u16* L, f32x4 acc[8][4])
{
  constexpr int NKT = KT / 32;
  const int tid  = threadIdx.x;
  const int lane = tid & 63;
  const int wv   = tid >> 6;            // 0..7
  const int wr = wv >> 2, wc = wv & 3;

  // staging source precompute (pre-swizzled, (row>>1)&3 pattern)
  int grow[4], gcol[4];
#pragma unroll
  for (int i = 0; i < 4; i++) {
    int oi   = (tid + (i & 1) * 512) * 16;           // linear byte off in 16KB
    int loff = oi ^ (((oi >> 7) & 3) << 4);          // logical position
    grow[i] = loff >> 6;                             // row 0..255
    gcol[i] = (loff & 63) >> 1;                      // col element 0..31
  }
  const int W0 = wv * 1024;             // wave-uniform LDS byte base, load 0/2
  const int W1 = wv * 1024 + 8192;      // load 1/3

  // swizzled ds_read bases: ((lane>>4) ^ ((row>>1)&3))<<4 — 2-way, free
  const int rowA  = wr * 128 + (lane & 15);
  const int baseA = rowA * 64 + ((((lane >> 4)) ^ ((rowA >> 1) & 3)) << 4);
  const int rowB  = wc * 64 + (lane & 15);
  const int baseB = 16384 + rowB * 64 + ((((lane >> 4)) ^ ((rowB >> 1) & 3)) << 4);

  // prologue: stage tiles 0,1,2 (12 loads/wave); wait tile 0 (vmcnt(8))
#pragma unroll
  for (int tt = 0; tt < 3; tt++) {
    STG1(tt, 0, 0); STG1(tt, 1, 0); STG1(tt, 2, 1); STG1(tt, 3, 1);
  }
  __builtin_amdgcn_sched_barrier(0);
  asm volatile("s_waitcnt vmcnt(8)" ::: "memory");
  __builtin_amdgcn_s_barrier();
  FENCE();

  for (int j = 0; j < NKT - 3; ++j)
    KBODY(j, "s_waitcnt vmcnt(8)", 1);
  KBODY(NKT - 3, "s_waitcnt vmcnt(4)", 0);
  KBODY(NKT - 2, "s_waitcnt vmcnt(0)", 0);
  KBODY(NKT - 1, "", 0);
}

// P[q][p] = exp(S'[q][p] - MHAT); also per-column partial sums -> pstats.
// S' = (sum_f Q[q,f] K[p,f]) * INV_SCALE  (A=Q, B=K)  256x256 tiles
__global__ __launch_bounds__(512, 2) void qk256_kernel(
    const u16* __restrict__ kb, const u16* __restrict__ qb,
    u16* __restrict__ Pb, float* __restrict__ pstats)
{
  extern __shared__ u16 L[];            // 128 KB dynamic
  int bid = blockIdx.x;                 // 512 blocks, XCD-swizzled
  int xcd = bid & 7, r = bid >> 3;      // r: 0..63
  int bh  = xcd * 4 + (r >> 4);
  int til = r & 15;
  int mt  = til >> 2, nt = til & 3;

  const u16* Ag = qb + (size_t)bh * NP * NF + (size_t)mt * 256 * NF;
  const u16* Bg = kb + (size_t)bh * NP * NF + (size_t)nt * 256 * NF;

  f32x4 acc[8][4];
#pragma unroll
  for (int a = 0; a < 8; a++)
#pragma unroll
    for (int c = 0; c < 4; c++) acc[a][c] = (f32x4){0.f, 0.f, 0.f, 0.f};

  core256<NF>(Ag, Bg, L, acc);

  const int tid  = threadIdx.x;
  const int lane = tid & 63, wv = tid >> 6;
  const int wr = wv >> 2, wc = wv & 3;
  u16* Pp = Pb + (size_t)bh * NP * NP;

  float l4[4] = {0.f, 0.f, 0.f, 0.f};
#pragma unroll
  for (int mf = 0; mf < 8; mf++)
#pragma unroll
    for (int jj = 0; jj < 4; jj++) {
      int m = mt * 256 + wr * 128 + mf * 16 + (lane >> 4) * 4 + jj;   // q
#pragma unroll
      for (int nf = 0; nf < 4; nf++) {
        int n = nt * 256 + wc * 64 + nf * 16 + (lane & 15);           // p
        float e = __expf(acc[mf][nf][jj] * INV_SCALE - MHAT);
        l4[nf] += e;
        Pp[(size_t)m * NP + n] = f2bf(e);
      }
    }

  // reduce l over lanes sharing the same column (lane&15): xor 16, 32
#pragma unroll
  for (int nf = 0; nf < 4; nf++) {
    l4[nf] += __shfl_xor(l4[nf], 16);
    l4[nf] += __shfl_xor(l4[nf], 32);
  }
  // cross-wave (wr) combine via LDS (L is free after core256's final barrier)
  float* st = (float*)L;                // [2][256]
  __syncthreads();
  if (lane < 16) {
#pragma unroll
    for (int nf = 0; nf < 4; nf++)
      st[wr * 256 + wc * 64 + nf * 16 + lane] = l4[nf];
  }
  __syncthreads();
  if (tid < 256) {
    float s = st[tid] + st[256 + tid];
    pstats[((bh * 4 + mt) << 10) + nt * 256 + tid] = s;
  }
}

// sscale[bh][p] = 1 / sum_mt pstats[bh][mt][p]
__global__ __launch_bounds__(256) void statsfin_kernel(
    const float* __restrict__ pstats, float* __restrict__ sscale)
{
  int idx = blockIdx.x * 256 + threadIdx.x;    // 32768
  int bh = idx >> 10, p = idx & 1023;
  const float* pp = pstats + (size_t)bh * 4096 + p;
  float s = pp[0] + pp[1024] + pp[2048] + pp[3072];
  sscale[idx] = 1.0f / s;
}

// Out[q][f] = sum_p P[q,p] * VtScaled[f,p];  write fp32 out[b][h*32+d][q][t]
__global__ __launch_bounds__(512, 2) void av256_kernel(
    const u16* __restrict__ Pb, const u16* __restrict__ Vt, float* __restrict__ out)
{
  extern __shared__ u16 L[];            // 128 KB dynamic
  int bid = blockIdx.x;                 // 1024 blocks, XCD-swizzled
  int xcd = bid & 7, r = bid >> 3;      // r: 0..127
  int bh  = xcd * 4 + (r >> 5);
  int til = r & 31;
  int mt  = til >> 3, ntf = til & 7;

  const u16* Ag = Pb + (size_t)bh * NP * NP + (size_t)mt * 256 * NP;
  const u16* Bg = Vt + (size_t)bh * NF * NP + (size_t)ntf * 256 * NP;

  f32x4 acc[8][4];
#pragma unroll
  for (int a = 0; a < 8; a++)
#pragma unroll
    for (int c = 0; c < 4; c++) acc[a][c] = (f32x4){0.f, 0.f, 0.f, 0.f};

  core256<NP>(Ag, Bg, L, acc);

  const int lane = threadIdx.x & 63, wv = threadIdx.x >> 6;
  const int wr = wv >> 2, wc = wv & 3;
  int b = bh >> 3, h = bh & 7;
#pragma unroll
  for (int mf = 0; mf < 8; mf++)
#pragma unroll
    for (int jj = 0; jj < 4; jj++) {
      int m = mt * 256 + wr * 128 + mf * 16 + (lane >> 4) * 4 + jj;   // q
#pragma unroll
      for (int nf = 0; nf < 4; nf++) {
        int n = ntf * 256 + wc * 64 + nf * 16 + (lane & 15);          // f
        int dd = n >> 6, t = n & 63;
        out[((size_t)(b * NC + h * ND + dd) * NP + m) * NT + t] = acc[mf][nf][jj];
      }
    }
}

// ---------------------------------------------------------------------------
extern "C" void kernel_launch(void* const* d_in, const int* in_sizes, int n_in,
                              void* d_out, int out_size, void* d_ws, size_t ws_size,
                              hipStream_t stream)
{
  if (ws_size < 4ull * KQV_ELEMS * sizeof(u16)) return;  // need 537 MB scratch

  const float* x  = (const float*)d_in[0];
  const float* Wk = (const float*)d_in[1];
  const float* bk = (const float*)d_in[2];
  const float* Wq = (const float*)d_in[3];
  const float* bq = (const float*)d_in[4];
  const float* Wv = (const float*)d_in[5];
  const float* bv = (const float*)d_in[6];

  // ws layout (lifetimes):
  //  slot0: kb [bh][p][f]   (proj->qk), then vt [bh][f][p] (transpose->av)
  //  slot1: qb [bh][p][f]   (proj->qk)
  //  slot2: vb [bh][p][f]   (proj->transpose)
  //  slot3: Pb [bh][q][p] (67MB) + pstats (512KB) + sscale (128KB)  (qk->av)
  u16* kb = (u16*)d_ws;
  u16* qb = kb + KQV_ELEMS;
  u16* vb = kb + 2 * KQV_ELEMS;
  u16* Pb = kb + 3 * KQV_ELEMS;            // 33,554,432 u16
  float* pstats = (float*)(Pb + 33554432); // [bh][4][1024]
  float* sscale = pstats + 131072;         // [bh][1024]
  u16* vt = kb;                            // reuse slot0 after qk

  // d_out head staging: xT (134 MB) + wbf (0.4 MB); dead before av writes.
  u16* xT  = (u16*)d_out;                  // [(b,pt)][c]
  u16* wbf = xT + KQV_ELEMS;               // 3 x 256 x 256

  (void)hipFuncSetAttribute((const void*)qk256_kernel,
                            hipFuncAttributeMaxDynamicSharedMemorySize, 131072);
  (void)hipFuncSetAttribute((const void*)av256_kernel,
                            hipFuncAttributeMaxDynamicSharedMemorySize, 131072);

  wcast_kernel<<<dim3(64, 3), 256, 0, stream>>>(Wk, Wq, Wv, wbf);
  xcast_kernel<<<dim3(1024, 4, 4), 256, 0, stream>>>(x, xT);
  proj1024_kernel<<<dim3(768, 4), 1024, 0, stream>>>(wbf, xT, bk, bq, bv, kb);
  qk256_kernel<<<dim3(512), 512, 131072, stream>>>(kb, qb, Pb, pstats);
  statsfin_kernel<<<dim3(128), 256, 0, stream>>>(pstats, sscale);
  transpose_kernel<<<dim3(32, 16, 32), 256, 0, stream>>>(vb, vt, sscale);
  av256_kernel<<<dim3(1024), 512, 131072, stream>>>(Pb, vt, (float*)d_out);
}